// Round 2
// baseline (396.724 us; speedup 1.0000x reference)
//
#include <hip/hip_runtime.h>
#include <stdint.h>

#define HIDDEN 1536
#define NHEAD 12
#define HD 128
#define TSEQ 2048
#define NROWS 4096
#define KDIM HIDDEN
#define EPS_F 1.1920928955078125e-07f
// (1/sqrt(128)) * log2(e)
#define SCALE_LOG2E 0.12751879110195655f

typedef unsigned short u16;
typedef __bf16 bf16x8_t __attribute__((ext_vector_type(8)));
typedef float f32x4_t __attribute__((ext_vector_type(4)));

#define MFMA16(a, b, c) __builtin_amdgcn_mfma_f32_16x16x32_bf16((a), (b), (c), 0, 0, 0)

__device__ __forceinline__ u16 f2bf(float f) {
  unsigned u = __builtin_bit_cast(unsigned, f);
  u = (u + 0x7fffu + ((u >> 16) & 1u)) >> 16;
  return (u16)u;
}

// ---------------- cast fp32 -> bf16 (vectorized) ----------------
__global__ __launch_bounds__(256) void cast_kernel(const float* __restrict__ in,
                                                   u16* __restrict__ out, int n) {
  int i = (blockIdx.x * 256 + threadIdx.x) * 4;
  if (i >= n) return;
  float4 v = *reinterpret_cast<const float4*>(in + i);
  uint2 pk;
  pk.x = (unsigned)f2bf(v.x) | ((unsigned)f2bf(v.y) << 16);
  pk.y = (unsigned)f2bf(v.z) | ((unsigned)f2bf(v.w) << 16);
  *reinterpret_cast<uint2*>(out + i) = pk;
}

// ---------------- shared NT-GEMM mainloop: C[128x128] = A[128xK] * W[128xK]^T ----------------
// All matrices have leading dim KDIM=1536. bf16 in, fp32 acc.
__device__ __forceinline__ void stage_tile(const u16* __restrict__ src, int row0, int k0,
                                           u16* lds, int w, int l) {
#pragma unroll
  for (int i = 0; i < 2; ++i) {
    int chunk = w * 128 + i * 64 + l;  // 512 chunks of 8 bf16 = 128x32 tile
    int row = chunk >> 2;
    int kc = (chunk & 3) * 8;
    __builtin_amdgcn_global_load_lds(
        (const __attribute__((address_space(1))) void*)(src + (row0 + row) * KDIM + k0 + kc),
        (__attribute__((address_space(3))) void*)(lds + w * 1024 + i * 512), 16, 0, 0);
  }
}

__device__ __forceinline__ void gemm_mainloop(const u16* __restrict__ A,
                                              const u16* __restrict__ W, int M0, int N0,
                                              u16* lA, u16* lW, f32x4_t acc[4][4], int tid) {
  const int w = tid >> 6, l = tid & 63;
  const int lrow = l & 15, kg = l >> 4;
  const int wr = (w >> 1) * 64, wc = (w & 1) * 64;
  stage_tile(A, M0, 0, lA, w, l);
  stage_tile(W, N0, 0, lW, w, l);
  const int NT = KDIM / 32;
#pragma unroll 1
  for (int kt = 0; kt < NT; ++kt) {
    const int cur = kt & 1;
    if (kt + 1 < NT) {
      stage_tile(A, M0, (kt + 1) * 32, lA + (cur ^ 1) * 4096, w, l);
      stage_tile(W, N0, (kt + 1) * 32, lW + (cur ^ 1) * 4096, w, l);
      asm volatile("s_waitcnt vmcnt(4)" ::: "memory");  // current buffer's 4 loads done
    } else {
      asm volatile("s_waitcnt vmcnt(0)" ::: "memory");
    }
    __builtin_amdgcn_s_barrier();
    asm volatile("" ::: "memory");
    const u16* Ab = lA + cur * 4096;
    const u16* Wb = lW + cur * 4096;
    bf16x8_t af[4], bf_[4];
#pragma unroll
    for (int m = 0; m < 4; ++m)
      af[m] = *reinterpret_cast<const bf16x8_t*>(Ab + (wr + m * 16 + lrow) * 32 + kg * 8);
#pragma unroll
    for (int n = 0; n < 4; ++n)
      bf_[n] = *reinterpret_cast<const bf16x8_t*>(Wb + (wc + n * 16 + lrow) * 32 + kg * 8);
#pragma unroll
    for (int m = 0; m < 4; ++m)
#pragma unroll
      for (int n = 0; n < 4; ++n)
        acc[m][n] = MFMA16(af[m], bf_[n], acc[m][n]);
    asm volatile("s_waitcnt lgkmcnt(0)" ::: "memory");
    __builtin_amdgcn_s_barrier();
    asm volatile("" ::: "memory");
  }
}

// ---------------- QKV projection; z selects weight + epilogue ----------------
__global__ __launch_bounds__(256) void gemm_qkv_kernel(
    const u16* __restrict__ xb, const u16* __restrict__ wq, const u16* __restrict__ wk,
    const u16* __restrict__ wv, float* __restrict__ qf, float* __restrict__ kf,
    u16* __restrict__ vt) {
  __shared__ __align__(16) u16 lA[8192], lW[8192];
  const int tid = threadIdx.x;
  const int M0 = blockIdx.y * 128, N0 = blockIdx.x * 128;
  const int z = blockIdx.z;
  const u16* W = (z == 0) ? wq : (z == 1) ? wk : wv;
  f32x4_t acc[4][4] = {};
  gemm_mainloop(xb, W, M0, N0, lA, lW, acc, tid);
  const int w = tid >> 6, l = tid & 63;
  const int lrow = l & 15, kg = l >> 4;
  const int wr = (w >> 1) * 64, wc = (w & 1) * 64;
  const int h = blockIdx.x;  // BN = 128 = HD: one tile column == one head
#pragma unroll
  for (int m = 0; m < 4; ++m)
#pragma unroll
    for (int n = 0; n < 4; ++n)
#pragma unroll
      for (int r = 0; r < 4; ++r) {
        const int grow = M0 + wr + m * 16 + kg * 4 + r;  // token row in [0,4096)
        const int d = wc + n * 16 + lrow;                // 0..127 within head
        const int bb = grow >> 11, t = grow & (TSEQ - 1);
        const float v = acc[m][n][r];
        if (z == 2) {
          // V stored transposed: [b][h][d][t] bf16 (PV B-frags contiguous)
          vt[((size_t)(bb * NHEAD + h) * HD + d) * TSEQ + t] = f2bf(v);
        } else {
          float* dstp = (z == 0) ? qf : kf;
          dstp[((size_t)(bb * NHEAD + h) * TSEQ + t) * HD + d] = v;
        }
      }
}

// ---------------- output projection ----------------
__global__ __launch_bounds__(256) void gemm_out_kernel(const u16* __restrict__ yh,
                                                       const u16* __restrict__ wp,
                                                       float* __restrict__ out) {
  __shared__ __align__(16) u16 lA[8192], lW[8192];
  const int tid = threadIdx.x;
  const int M0 = blockIdx.y * 128, N0 = blockIdx.x * 128;
  f32x4_t acc[4][4] = {};
  gemm_mainloop(yh, wp, M0, N0, lA, lW, acc, tid);
  const int w = tid >> 6, l = tid & 63;
  const int lrow = l & 15, kg = l >> 4;
  const int wr = (w >> 1) * 64, wc = (w & 1) * 64;
#pragma unroll
  for (int m = 0; m < 4; ++m)
#pragma unroll
    for (int n = 0; n < 4; ++n)
#pragma unroll
      for (int r = 0; r < 4; ++r) {
        const int grow = M0 + wr + m * 16 + kg * 4 + r;
        const int gcol = N0 + wc + n * 16 + lrow;
        out[(size_t)grow * HIDDEN + gcol] = acc[m][n][r];
      }
}

// ---------------- RoPE + RMSNorm (fp32 in, bf16 out, head layout) ----------------
__global__ __launch_bounds__(256) void rope_rms_kernel(
    const float* __restrict__ qf, const float* __restrict__ kf, const float* __restrict__ cosp,
    const float* __restrict__ sinp, u16* __restrict__ qh, u16* __restrict__ kh) {
  const int w = threadIdx.x >> 6, l = threadIdx.x & 63;
  const int row = blockIdx.x * 4 + w;  // (b*NH+h)*T + t
  const int t = row & (TSEQ - 1);
  const float* src = blockIdx.y ? kf : qf;
  u16* dst = blockIdx.y ? kh : qh;
  const size_t base = (size_t)row * HD;
  float x1 = src[base + l];
  float x2 = src[base + 64 + l];
  float c = cosp[t * 64 + l], s = sinp[t * 64 + l];
  float y1 = x1 * c + x2 * s;
  float y2 = x2 * c - x1 * s;
  float ss = y1 * y1 + y2 * y2;
#pragma unroll
  for (int off = 1; off < 64; off <<= 1) ss += __shfl_xor(ss, off, 64);
  float rinv = rsqrtf(ss * (1.0f / 128.0f) + EPS_F);
  dst[base + l] = f2bf(y1 * rinv);
  dst[base + 64 + l] = f2bf(y2 * rinv);
}

// ---------------- flash attention with causal + sliding window ----------------
__global__ __launch_bounds__(256) void attn_kernel(const u16* __restrict__ qh,
                                                   const u16* __restrict__ kh,
                                                   const u16* __restrict__ vt,
                                                   u16* __restrict__ yh,
                                                   const int* __restrict__ winp) {
  __shared__ __align__(16) u16 Pl[4][2048];  // per-wave 32x64 bf16 P tile (XOR-swizzled)
  const int tid = threadIdx.x, w = tid >> 6, l = tid & 63;
  const int lrow = l & 15, kg = l >> 4;
  const int q0 = blockIdx.x * 128;
  const int h = blockIdx.y, b = blockIdx.z;
  const int win = winp[0];
  const size_t bh = (size_t)(b * NHEAD + h);
  const u16* Q = qh + bh * TSEQ * HD;
  const u16* K = kh + bh * TSEQ * HD;
  const u16* V = vt + bh * (size_t)HD * TSEQ;
  const int qw = q0 + w * 32;
  // hoist Q fragments (32 rows x 128 d per wave)
  bf16x8_t aq[2][4];
#pragma unroll
  for (int m = 0; m < 2; ++m)
#pragma unroll
    for (int ks = 0; ks < 4; ++ks)
      aq[m][ks] =
          *reinterpret_cast<const bf16x8_t*>(Q + (qw + m * 16 + lrow) * HD + ks * 32 + kg * 8);
  float mrun[2][4], lrun[2][4];
  f32x4_t accv[2][8] = {};
#pragma unroll
  for (int m = 0; m < 2; ++m)
#pragma unroll
    for (int r = 0; r < 4; ++r) {
      mrun[m][r] = -1e30f;
      lrun[m][r] = 0.0f;
    }
  int lo = q0 - win;
  if (lo < 0) lo = 0;
  lo &= ~63;
  const int hi = q0 + 127;
  u16* Pw = &Pl[w][0];
  for (int kv = lo; kv <= hi; kv += 64) {
    // ---- S = Q K^T (32 x 64) ----
    f32x4_t s[2][4] = {};
#pragma unroll
    for (int n = 0; n < 4; ++n) {
#pragma unroll
      for (int ks = 0; ks < 4; ++ks) {
        bf16x8_t bk = *reinterpret_cast<const bf16x8_t*>(K + (kv + n * 16 + lrow) * HD +
                                                         ks * 32 + kg * 8);
        s[0][n] = MFMA16(aq[0][ks], bk, s[0][n]);
        s[1][n] = MFMA16(aq[1][ks], bk, s[1][n]);
      }
    }
    // ---- mask + online softmax (fp32) ----
#pragma unroll
    for (int m = 0; m < 2; ++m) {
#pragma unroll
      for (int n = 0; n < 4; ++n) {
        const int key = kv + n * 16 + lrow;
#pragma unroll
        for (int r = 0; r < 4; ++r) {
          const int rowq = qw + m * 16 + kg * 4 + r;
          if (!(key <= rowq && rowq - key <= win)) s[m][n][r] = -1e30f;
        }
      }
      float mx[4], psum[4], alpha[4];
#pragma unroll
      for (int r = 0; r < 4; ++r)
        mx[r] = fmaxf(fmaxf(s[m][0][r], s[m][1][r]), fmaxf(s[m][2][r], s[m][3][r]));
#pragma unroll
      for (int off = 1; off < 16; off <<= 1)
#pragma unroll
        for (int r = 0; r < 4; ++r) mx[r] = fmaxf(mx[r], __shfl_xor(mx[r], off, 64));
#pragma unroll
      for (int r = 0; r < 4; ++r) {
        float mn = fmaxf(mrun[m][r], mx[r]);
        alpha[r] = exp2f((mrun[m][r] - mn) * SCALE_LOG2E);
        mrun[m][r] = mn;
      }
      float ps[4][4];
#pragma unroll
      for (int n = 0; n < 4; ++n)
#pragma unroll
        for (int r = 0; r < 4; ++r) ps[n][r] = exp2f((s[m][n][r] - mrun[m][r]) * SCALE_LOG2E);
#pragma unroll
      for (int r = 0; r < 4; ++r) psum[r] = (ps[0][r] + ps[1][r]) + (ps[2][r] + ps[3][r]);
#pragma unroll
      for (int off = 1; off < 16; off <<= 1)
#pragma unroll
        for (int r = 0; r < 4; ++r) psum[r] += __shfl_xor(psum[r], off, 64);
#pragma unroll
      for (int r = 0; r < 4; ++r) lrun[m][r] = lrun[m][r] * alpha[r] + psum[r];
#pragma unroll
      for (int dn = 0; dn < 8; ++dn) {
        f32x4_t t = accv[m][dn];
        t[0] *= alpha[0];
        t[1] *= alpha[1];
        t[2] *= alpha[2];
        t[3] *= alpha[3];
        accv[m][dn] = t;
      }
      // write P (bf16) to swizzled per-wave LDS: D-frag -> A-frag layout conversion
#pragma unroll
      for (int n = 0; n < 4; ++n)
#pragma unroll
        for (int r = 0; r < 4; ++r) {
          const int rp = m * 16 + kg * 4 + r;
          int bofs = rp * 128 + (n * 16 + lrow) * 2;
          bofs ^= (rp & 7) << 4;
          *reinterpret_cast<u16*>(reinterpret_cast<char*>(Pw) + bofs) = f2bf(ps[n][r]);
        }
    }
    asm volatile("s_waitcnt lgkmcnt(0)" ::: "memory");
    // ---- O += P V ----
#pragma unroll
    for (int ks2 = 0; ks2 < 2; ++ks2) {
      bf16x8_t ap[2];
#pragma unroll
      for (int m = 0; m < 2; ++m) {
        const int rp = m * 16 + lrow;
        int bofs = rp * 128 + ks2 * 64 + kg * 16;
        bofs ^= (rp & 7) << 4;
        ap[m] = *reinterpret_cast<const bf16x8_t*>(reinterpret_cast<const char*>(Pw) + bofs);
      }
#pragma unroll
      for (int dn = 0; dn < 8; ++dn) {
        bf16x8_t bv = *reinterpret_cast<const bf16x8_t*>(V + (size_t)(dn * 16 + lrow) * TSEQ +
                                                         kv + ks2 * 32 + kg * 8);
        accv[0][dn] = MFMA16(ap[0], bv, accv[0][dn]);
        accv[1][dn] = MFMA16(ap[1], bv, accv[1][dn]);
      }
    }
  }
  // epilogue: divide by row sums, write y bf16 [4096][1536]
#pragma unroll
  for (int m = 0; m < 2; ++m) {
    float inv[4];
#pragma unroll
    for (int r = 0; r < 4; ++r) inv[r] = 1.0f / lrun[m][r];
#pragma unroll
    for (int dn = 0; dn < 8; ++dn)
#pragma unroll
      for (int r = 0; r < 4; ++r) {
        const int rowg = b * TSEQ + qw + m * 16 + kg * 4 + r;
        const int col = h * HD + dn * 16 + lrow;
        yh[(size_t)rowg * HIDDEN + col] = f2bf(accv[m][dn][r] * inv[r]);
      }
  }
}

extern "C" void kernel_launch(void* const* d_in, const int* in_sizes, int n_in, void* d_out,
                              int out_size, void* d_ws, size_t ws_size, hipStream_t stream) {
  const float* x = (const float*)d_in[0];
  const float* cosp = (const float*)d_in[1];
  const float* sinp = (const float*)d_in[2];
  const float* Wq = (const float*)d_in[3];
  const float* Wk = (const float*)d_in[4];
  const float* Wv = (const float*)d_in[5];
  const float* Wp = (const float*)d_in[6];
  const int* winp = (const int*)d_in[7];

  char* ws = (char*)d_ws;
  size_t off = 0;
  auto alloc = [&](size_t bytes) {
    char* p = ws + off;
    off += (bytes + 255) & ~(size_t)255;
    return p;
  };
  u16* xb = (u16*)alloc((size_t)NROWS * HIDDEN * 2);
  u16* wqb = (u16*)alloc((size_t)HIDDEN * HIDDEN * 2);
  u16* wkb = (u16*)alloc((size_t)HIDDEN * HIDDEN * 2);
  u16* wvb = (u16*)alloc((size_t)HIDDEN * HIDDEN * 2);
  u16* wpb = (u16*)alloc((size_t)HIDDEN * HIDDEN * 2);
  float* qf = (float*)alloc((size_t)NROWS * HIDDEN * 4);
  float* kf = (float*)alloc((size_t)NROWS * HIDDEN * 4);
  u16* qh = (u16*)alloc((size_t)NROWS * HIDDEN * 2);
  u16* kh = (u16*)alloc((size_t)NROWS * HIDDEN * 2);
  u16* vt = (u16*)alloc((size_t)NROWS * HIDDEN * 2);
  u16* yh = (u16*)alloc((size_t)NROWS * HIDDEN * 2);

  const int nx = NROWS * HIDDEN;    // 6291456
  const int nw = HIDDEN * HIDDEN;   // 2359296
  cast_kernel<<<nx / 1024, 256, 0, stream>>>(x, xb, nx);
  cast_kernel<<<nw / 1024, 256, 0, stream>>>(Wq, wqb, nw);
  cast_kernel<<<nw / 1024, 256, 0, stream>>>(Wk, wkb, nw);
  cast_kernel<<<nw / 1024, 256, 0, stream>>>(Wv, wvb, nw);
  cast_kernel<<<nw / 1024, 256, 0, stream>>>(Wp, wpb, nw);

  gemm_qkv_kernel<<<dim3(HIDDEN / 128, NROWS / 128, 3), 256, 0, stream>>>(xb, wqb, wkb, wvb, qf,
                                                                          kf, vt);
  rope_rms_kernel<<<dim3((2 * NHEAD * TSEQ) / 4, 2), 256, 0, stream>>>(qf, kf, cosp, sinp, qh,
                                                                       kh);
  attn_kernel<<<dim3(TSEQ / 128, NHEAD, 2), 256, 0, stream>>>(qh, kh, vt, yh, winp);
  gemm_out_kernel<<<dim3(HIDDEN / 128, NROWS / 128), 256, 0, stream>>>(yh, wpb, (float*)d_out);
}

// Round 3
// 376.564 us; speedup vs baseline: 1.0535x; 1.0535x over previous
//
#include <hip/hip_runtime.h>
#include <stdint.h>

#define HIDDEN 1536
#define NHEAD 12
#define HD 128
#define TSEQ 2048
#define NROWS 4096
#define KDIM HIDDEN
#define EPS_F 1.1920928955078125e-07f
// (1/sqrt(128)) * log2(e)
#define SCALE_LOG2E 0.12751879110195655f
// fixed softmax shift (log2 domain): scores bounded by sqrt(128)=11.314 (RMS-normed
// q,k => |q||k|<=128 by Cauchy-Schwarz), *log2(e) = 16.32; use 16.6 for bf16 margin.
#define FIXSUB 16.6f

typedef unsigned short u16;
typedef __bf16 bf16x8_t __attribute__((ext_vector_type(8)));
typedef float f32x4_t __attribute__((ext_vector_type(4)));

#define MFMA16(a, b, c) __builtin_amdgcn_mfma_f32_16x16x32_bf16((a), (b), (c), 0, 0, 0)

__device__ __forceinline__ u16 f2bf(float f) {
  unsigned u = __builtin_bit_cast(unsigned, f);
  u = (u + 0x7fffu + ((u >> 16) & 1u)) >> 16;
  return (u16)u;
}

// ---------------- cast fp32 -> bf16 (vectorized) ----------------
__global__ __launch_bounds__(256) void cast_kernel(const float* __restrict__ in,
                                                   u16* __restrict__ out, int n) {
  int i = (blockIdx.x * 256 + threadIdx.x) * 4;
  if (i >= n) return;
  float4 v = *reinterpret_cast<const float4*>(in + i);
  uint2 pk;
  pk.x = (unsigned)f2bf(v.x) | ((unsigned)f2bf(v.y) << 16);
  pk.y = (unsigned)f2bf(v.z) | ((unsigned)f2bf(v.w) << 16);
  *reinterpret_cast<uint2*>(out + i) = pk;
}

// ---------------- shared NT-GEMM mainloop: C[128x128] = A[128xK] * W[128xK]^T ----------------
// All matrices have leading dim KDIM=1536. bf16 in, fp32 acc.
__device__ __forceinline__ void stage_tile(const u16* __restrict__ src, int row0, int k0,
                                           u16* lds, int w, int l) {
#pragma unroll
  for (int i = 0; i < 2; ++i) {
    int chunk = w * 128 + i * 64 + l;  // 512 chunks of 8 bf16 = 128x32 tile
    int row = chunk >> 2;
    int kc = (chunk & 3) * 8;
    __builtin_amdgcn_global_load_lds(
        (const __attribute__((address_space(1))) void*)(src + (row0 + row) * KDIM + k0 + kc),
        (__attribute__((address_space(3))) void*)(lds + w * 1024 + i * 512), 16, 0, 0);
  }
}

__device__ __forceinline__ void gemm_mainloop(const u16* __restrict__ A,
                                              const u16* __restrict__ W, int M0, int N0,
                                              u16* lA, u16* lW, f32x4_t acc[4][4], int tid) {
  const int w = tid >> 6, l = tid & 63;
  const int lrow = l & 15, kg = l >> 4;
  const int wr = (w >> 1) * 64, wc = (w & 1) * 64;
  stage_tile(A, M0, 0, lA, w, l);
  stage_tile(W, N0, 0, lW, w, l);
  const int NT = KDIM / 32;
#pragma unroll 1
  for (int kt = 0; kt < NT; ++kt) {
    const int cur = kt & 1;
    if (kt + 1 < NT) {
      stage_tile(A, M0, (kt + 1) * 32, lA + (cur ^ 1) * 4096, w, l);
      stage_tile(W, N0, (kt + 1) * 32, lW + (cur ^ 1) * 4096, w, l);
      asm volatile("s_waitcnt vmcnt(4)" ::: "memory");  // current buffer's 4 loads done
    } else {
      asm volatile("s_waitcnt vmcnt(0)" ::: "memory");
    }
    __builtin_amdgcn_s_barrier();
    asm volatile("" ::: "memory");
    const u16* Ab = lA + cur * 4096;
    const u16* Wb = lW + cur * 4096;
    bf16x8_t af[4], bf_[4];
#pragma unroll
    for (int m = 0; m < 4; ++m)
      af[m] = *reinterpret_cast<const bf16x8_t*>(Ab + (wr + m * 16 + lrow) * 32 + kg * 8);
#pragma unroll
    for (int n = 0; n < 4; ++n)
      bf_[n] = *reinterpret_cast<const bf16x8_t*>(Wb + (wc + n * 16 + lrow) * 32 + kg * 8);
#pragma unroll
    for (int m = 0; m < 4; ++m)
#pragma unroll
      for (int n = 0; n < 4; ++n)
        acc[m][n] = MFMA16(af[m], bf_[n], acc[m][n]);
    asm volatile("s_waitcnt lgkmcnt(0)" ::: "memory");
    __builtin_amdgcn_s_barrier();
    asm volatile("" ::: "memory");
  }
}

// ---------------- QKV projection; z selects weight + epilogue ----------------
__global__ __launch_bounds__(256) void gemm_qkv_kernel(
    const u16* __restrict__ xb, const u16* __restrict__ wq, const u16* __restrict__ wk,
    const u16* __restrict__ wv, float* __restrict__ qf, float* __restrict__ kf,
    u16* __restrict__ vt) {
  __shared__ __align__(16) u16 lA[8192], lW[8192];
  const int tid = threadIdx.x;
  const int M0 = blockIdx.y * 128, N0 = blockIdx.x * 128;
  const int z = blockIdx.z;
  const u16* W = (z == 0) ? wq : (z == 1) ? wk : wv;
  f32x4_t acc[4][4] = {};
  gemm_mainloop(xb, W, M0, N0, lA, lW, acc, tid);
  const int w = tid >> 6, l = tid & 63;
  const int lrow = l & 15, kg = l >> 4;
  const int wr = (w >> 1) * 64, wc = (w & 1) * 64;
  const int h = blockIdx.x;  // BN = 128 = HD: one tile column == one head
#pragma unroll
  for (int m = 0; m < 4; ++m)
#pragma unroll
    for (int n = 0; n < 4; ++n)
#pragma unroll
      for (int r = 0; r < 4; ++r) {
        const int grow = M0 + wr + m * 16 + kg * 4 + r;  // token row in [0,4096)
        const int d = wc + n * 16 + lrow;                // 0..127 within head
        const int bb = grow >> 11, t = grow & (TSEQ - 1);
        const float v = acc[m][n][r];
        if (z == 2) {
          // V stored transposed: [b][h][d][t] bf16 (PV B-frags contiguous)
          vt[((size_t)(bb * NHEAD + h) * HD + d) * TSEQ + t] = f2bf(v);
        } else {
          float* dstp = (z == 0) ? qf : kf;
          dstp[((size_t)(bb * NHEAD + h) * TSEQ + t) * HD + d] = v;
        }
      }
}

// ---------------- output projection ----------------
__global__ __launch_bounds__(256) void gemm_out_kernel(const u16* __restrict__ yh,
                                                       const u16* __restrict__ wp,
                                                       float* __restrict__ out) {
  __shared__ __align__(16) u16 lA[8192], lW[8192];
  const int tid = threadIdx.x;
  const int M0 = blockIdx.y * 128, N0 = blockIdx.x * 128;
  f32x4_t acc[4][4] = {};
  gemm_mainloop(yh, wp, M0, N0, lA, lW, acc, tid);
  const int w = tid >> 6, l = tid & 63;
  const int lrow = l & 15, kg = l >> 4;
  const int wr = (w >> 1) * 64, wc = (w & 1) * 64;
#pragma unroll
  for (int m = 0; m < 4; ++m)
#pragma unroll
    for (int n = 0; n < 4; ++n)
#pragma unroll
      for (int r = 0; r < 4; ++r) {
        const int grow = M0 + wr + m * 16 + kg * 4 + r;
        const int gcol = N0 + wc + n * 16 + lrow;
        out[(size_t)grow * HIDDEN + gcol] = acc[m][n][r];
      }
}

// ---------------- RoPE + RMSNorm (fp32 in, bf16 out, head layout) ----------------
__global__ __launch_bounds__(256) void rope_rms_kernel(
    const float* __restrict__ qf, const float* __restrict__ kf, const float* __restrict__ cosp,
    const float* __restrict__ sinp, u16* __restrict__ qh, u16* __restrict__ kh) {
  const int w = threadIdx.x >> 6, l = threadIdx.x & 63;
  const int row = blockIdx.x * 4 + w;  // (b*NH+h)*T + t
  const int t = row & (TSEQ - 1);
  const float* src = blockIdx.y ? kf : qf;
  u16* dst = blockIdx.y ? kh : qh;
  const size_t base = (size_t)row * HD;
  float x1 = src[base + l];
  float x2 = src[base + 64 + l];
  float c = cosp[t * 64 + l], s = sinp[t * 64 + l];
  float y1 = x1 * c + x2 * s;
  float y2 = x2 * c - x1 * s;
  float ss = y1 * y1 + y2 * y2;
#pragma unroll
  for (int off = 1; off < 64; off <<= 1) ss += __shfl_xor(ss, off, 64);
  float rinv = rsqrtf(ss * (1.0f / 128.0f) + EPS_F);
  dst[base + l] = f2bf(y1 * rinv);
  dst[base + 64 + l] = f2bf(y2 * rinv);
}

// ---------------- flash attention, causal + sliding window ----------------
// 16 q-rows per wave, 4 waves (64 q-rows) per block. Fixed-max softmax (no
// running max: post-RMS scores are bounded by sqrt(128) by construction).
// K loads batched at tile start; V loads issued right after QK MFMAs so their
// latency hides under the mask/exp/shuffle chain.
__global__ __launch_bounds__(256, 3) void attn_kernel(const u16* __restrict__ qh,
                                                      const u16* __restrict__ kh,
                                                      const u16* __restrict__ vt,
                                                      u16* __restrict__ yh,
                                                      const int* __restrict__ winp) {
  __shared__ __align__(16) u16 Pl[4][1024];  // per-wave 16x64 bf16 P tile (XOR-swizzled)
  const int tid = threadIdx.x, w = tid >> 6, l = tid & 63;
  const int lrow = l & 15, kg = l >> 4;
  const int qw = blockIdx.x * 64 + w * 16;  // this wave's 16 q-rows
  const int h = blockIdx.y, b = blockIdx.z;
  const int win = winp[0];
  const size_t bh = (size_t)(b * NHEAD + h);
  const u16* Q = qh + bh * TSEQ * HD;
  const u16* K = kh + bh * TSEQ * HD;
  const u16* V = vt + bh * (size_t)HD * TSEQ;
  // hoist Q fragments (16 rows x 128 d)
  bf16x8_t aq[4];
#pragma unroll
  for (int ks = 0; ks < 4; ++ks)
    aq[ks] = *reinterpret_cast<const bf16x8_t*>(Q + (qw + lrow) * HD + ks * 32 + kg * 8);
  float lrun[4] = {0.f, 0.f, 0.f, 0.f};
  f32x4_t accv[8] = {};
  int lo = qw - win;
  if (lo < 0) lo = 0;
  lo &= ~63;
  const int hi = qw + 15;
  u16* Pw = &Pl[w][0];
  for (int kv = lo; kv <= hi; kv += 64) {
    // ---- batched K fragment loads (64 keys x 128 d) ----
    bf16x8_t kf4[4][4];
#pragma unroll
    for (int n = 0; n < 4; ++n)
#pragma unroll
      for (int ks = 0; ks < 4; ++ks)
        kf4[n][ks] = *reinterpret_cast<const bf16x8_t*>(K + (kv + n * 16 + lrow) * HD +
                                                        ks * 32 + kg * 8);
    // ---- S = Q K^T (16 x 64) ----
    f32x4_t s[4] = {};
#pragma unroll
    for (int n = 0; n < 4; ++n)
#pragma unroll
      for (int ks = 0; ks < 4; ++ks) s[n] = MFMA16(aq[ks], kf4[n][ks], s[n]);
    // ---- issue V loads now: latency hides under softmax ----
    bf16x8_t vf[8][2];
#pragma unroll
    for (int dn = 0; dn < 8; ++dn)
#pragma unroll
      for (int k2 = 0; k2 < 2; ++k2)
        vf[dn][k2] = *reinterpret_cast<const bf16x8_t*>(V + (size_t)(dn * 16 + lrow) * TSEQ +
                                                        kv + k2 * 32 + kg * 8);
    // ---- mask + exp (fixed shift, no running max) ----
    float ps[4][4];
    float psum[4];
#pragma unroll
    for (int n = 0; n < 4; ++n) {
      const int key = kv + n * 16 + lrow;
#pragma unroll
      for (int r = 0; r < 4; ++r) {
        const int rowq = qw + kg * 4 + r;
        const bool ok = (key <= rowq) && (rowq - key <= win);
        ps[n][r] = ok ? exp2f(__builtin_fmaf(s[n][r], SCALE_LOG2E, -FIXSUB)) : 0.0f;
      }
    }
#pragma unroll
    for (int r = 0; r < 4; ++r) psum[r] = (ps[0][r] + ps[1][r]) + (ps[2][r] + ps[3][r]);
#pragma unroll
    for (int off = 1; off < 16; off <<= 1)
#pragma unroll
      for (int r = 0; r < 4; ++r) psum[r] += __shfl_xor(psum[r], off, 64);
#pragma unroll
    for (int r = 0; r < 4; ++r) lrun[r] += psum[r];
    // ---- P (bf16) -> swizzled per-wave LDS: D-frag -> A-frag layout ----
#pragma unroll
    for (int n = 0; n < 4; ++n)
#pragma unroll
      for (int r = 0; r < 4; ++r) {
        const int rp = kg * 4 + r;
        int bofs = rp * 128 + (n * 16 + lrow) * 2;
        bofs ^= (rp & 7) << 4;
        *reinterpret_cast<u16*>(reinterpret_cast<char*>(Pw) + bofs) = f2bf(ps[n][r]);
      }
    asm volatile("s_waitcnt lgkmcnt(0)" ::: "memory");
    // ---- O += P V ----
    bf16x8_t ap[2];
#pragma unroll
    for (int k2 = 0; k2 < 2; ++k2) {
      int bofs = lrow * 128 + k2 * 64 + kg * 16;
      bofs ^= (lrow & 7) << 4;
      ap[k2] = *reinterpret_cast<const bf16x8_t*>(reinterpret_cast<const char*>(Pw) + bofs);
    }
#pragma unroll
    for (int k2 = 0; k2 < 2; ++k2)
#pragma unroll
      for (int dn = 0; dn < 8; ++dn) accv[dn] = MFMA16(ap[k2], vf[dn][k2], accv[dn]);
  }
  // epilogue: divide by row sums, write y bf16 [4096][1536]
  float inv[4];
#pragma unroll
  for (int r = 0; r < 4; ++r) inv[r] = 1.0f / lrun[r];
#pragma unroll
  for (int dn = 0; dn < 8; ++dn)
#pragma unroll
    for (int r = 0; r < 4; ++r) {
      const int rowg = b * TSEQ + qw + kg * 4 + r;
      const int col = h * HD + dn * 16 + lrow;
      yh[(size_t)rowg * HIDDEN + col] = f2bf(accv[dn][r] * inv[r]);
    }
}

extern "C" void kernel_launch(void* const* d_in, const int* in_sizes, int n_in, void* d_out,
                              int out_size, void* d_ws, size_t ws_size, hipStream_t stream) {
  const float* x = (const float*)d_in[0];
  const float* cosp = (const float*)d_in[1];
  const float* sinp = (const float*)d_in[2];
  const float* Wq = (const float*)d_in[3];
  const float* Wk = (const float*)d_in[4];
  const float* Wv = (const float*)d_in[5];
  const float* Wp = (const float*)d_in[6];
  const int* winp = (const int*)d_in[7];

  char* ws = (char*)d_ws;
  size_t off = 0;
  auto alloc = [&](size_t bytes) {
    char* p = ws + off;
    off += (bytes + 255) & ~(size_t)255;
    return p;
  };
  u16* xb = (u16*)alloc((size_t)NROWS * HIDDEN * 2);
  u16* wqb = (u16*)alloc((size_t)HIDDEN * HIDDEN * 2);
  u16* wkb = (u16*)alloc((size_t)HIDDEN * HIDDEN * 2);
  u16* wvb = (u16*)alloc((size_t)HIDDEN * HIDDEN * 2);
  u16* wpb = (u16*)alloc((size_t)HIDDEN * HIDDEN * 2);
  float* qf = (float*)alloc((size_t)NROWS * HIDDEN * 4);
  float* kf = (float*)alloc((size_t)NROWS * HIDDEN * 4);
  u16* qh = (u16*)alloc((size_t)NROWS * HIDDEN * 2);
  u16* kh = (u16*)alloc((size_t)NROWS * HIDDEN * 2);
  u16* vt = (u16*)alloc((size_t)NROWS * HIDDEN * 2);
  u16* yh = (u16*)alloc((size_t)NROWS * HIDDEN * 2);

  const int nx = NROWS * HIDDEN;    // 6291456
  const int nw = HIDDEN * HIDDEN;   // 2359296
  cast_kernel<<<nx / 1024, 256, 0, stream>>>(x, xb, nx);
  cast_kernel<<<nw / 1024, 256, 0, stream>>>(Wq, wqb, nw);
  cast_kernel<<<nw / 1024, 256, 0, stream>>>(Wk, wkb, nw);
  cast_kernel<<<nw / 1024, 256, 0, stream>>>(Wv, wvb, nw);
  cast_kernel<<<nw / 1024, 256, 0, stream>>>(Wp, wpb, nw);

  gemm_qkv_kernel<<<dim3(HIDDEN / 128, NROWS / 128, 3), 256, 0, stream>>>(xb, wqb, wkb, wvb, qf,
                                                                          kf, vt);
  rope_rms_kernel<<<dim3((2 * NHEAD * TSEQ) / 4, 2), 256, 0, stream>>>(qf, kf, cosp, sinp, qh,
                                                                       kh);
  attn_kernel<<<dim3(TSEQ / 64, NHEAD, 2), 256, 0, stream>>>(qh, kh, vt, yh, winp);
  gemm_out_kernel<<<dim3(HIDDEN / 128, NROWS / 128), 256, 0, stream>>>(yh, wpb, (float*)d_out);
}

// Round 4
// 255.484 us; speedup vs baseline: 1.5528x; 1.4739x over previous
//
#include <hip/hip_runtime.h>
#include <stdint.h>

#define HIDDEN 1536
#define NHEAD 12
#define HD 128
#define TSEQ 2048
#define NROWS 4096
#define KDIM HIDDEN
#define EPS_F 1.1920928955078125e-07f
// (1/sqrt(128)) * log2(e)
#define SCALE_LOG2E 0.12751879110195655f
// fixed softmax shift (log2 domain): scores bounded by sqrt(128)=11.314 (RMS-normed
// q,k => |q||k|<=128 by Cauchy-Schwarz), *log2(e) = 16.32; use 16.6 for bf16 margin.
#define FIXSUB 16.6f

typedef unsigned short u16;
typedef __bf16 bf16x8_t __attribute__((ext_vector_type(8)));
typedef float f32x4_t __attribute__((ext_vector_type(4)));

#define MFMA16(a, b, c) __builtin_amdgcn_mfma_f32_16x16x32_bf16((a), (b), (c), 0, 0, 0)

__device__ __forceinline__ u16 f2bf(float f) {
  unsigned u = __builtin_bit_cast(unsigned, f);
  u = (u + 0x7fffu + ((u >> 16) & 1u)) >> 16;
  return (u16)u;
}

// ---------------- cast fp32 -> bf16 (vectorized) ----------------
__global__ __launch_bounds__(256) void cast_kernel(const float* __restrict__ in,
                                                   u16* __restrict__ out, int n) {
  int i = (blockIdx.x * 256 + threadIdx.x) * 4;
  if (i >= n) return;
  float4 v = *reinterpret_cast<const float4*>(in + i);
  uint2 pk;
  pk.x = (unsigned)f2bf(v.x) | ((unsigned)f2bf(v.y) << 16);
  pk.y = (unsigned)f2bf(v.z) | ((unsigned)f2bf(v.w) << 16);
  *reinterpret_cast<uint2*>(out + i) = pk;
}

// ---------------- shared NT-GEMM mainloop: C[128x128] = A[128xK] * W[128xK]^T ----------------
// All matrices have leading dim KDIM=1536. bf16 in, fp32 acc.
__device__ __forceinline__ void stage_tile(const u16* __restrict__ src, int row0, int k0,
                                           u16* lds, int w, int l) {
#pragma unroll
  for (int i = 0; i < 2; ++i) {
    int chunk = w * 128 + i * 64 + l;  // 512 chunks of 8 bf16 = 128x32 tile
    int row = chunk >> 2;
    int kc = (chunk & 3) * 8;
    __builtin_amdgcn_global_load_lds(
        (const __attribute__((address_space(1))) void*)(src + (row0 + row) * KDIM + k0 + kc),
        (__attribute__((address_space(3))) void*)(lds + w * 1024 + i * 512), 16, 0, 0);
  }
}

__device__ __forceinline__ void gemm_mainloop(const u16* __restrict__ A,
                                              const u16* __restrict__ W, int M0, int N0,
                                              u16* lA, u16* lW, f32x4_t acc[4][4], int tid) {
  const int w = tid >> 6, l = tid & 63;
  const int lrow = l & 15, kg = l >> 4;
  const int wr = (w >> 1) * 64, wc = (w & 1) * 64;
  stage_tile(A, M0, 0, lA, w, l);
  stage_tile(W, N0, 0, lW, w, l);
  const int NT = KDIM / 32;
#pragma unroll 1
  for (int kt = 0; kt < NT; ++kt) {
    const int cur = kt & 1;
    if (kt + 1 < NT) {
      stage_tile(A, M0, (kt + 1) * 32, lA + (cur ^ 1) * 4096, w, l);
      stage_tile(W, N0, (kt + 1) * 32, lW + (cur ^ 1) * 4096, w, l);
      asm volatile("s_waitcnt vmcnt(4)" ::: "memory");  // current buffer's 4 loads done
    } else {
      asm volatile("s_waitcnt vmcnt(0)" ::: "memory");
    }
    __builtin_amdgcn_s_barrier();
    asm volatile("" ::: "memory");
    const u16* Ab = lA + cur * 4096;
    const u16* Wb = lW + cur * 4096;
    bf16x8_t af[4], bf_[4];
#pragma unroll
    for (int m = 0; m < 4; ++m)
      af[m] = *reinterpret_cast<const bf16x8_t*>(Ab + (wr + m * 16 + lrow) * 32 + kg * 8);
#pragma unroll
    for (int n = 0; n < 4; ++n)
      bf_[n] = *reinterpret_cast<const bf16x8_t*>(Wb + (wc + n * 16 + lrow) * 32 + kg * 8);
#pragma unroll
    for (int m = 0; m < 4; ++m)
#pragma unroll
      for (int n = 0; n < 4; ++n)
        acc[m][n] = MFMA16(af[m], bf_[n], acc[m][n]);
    asm volatile("s_waitcnt lgkmcnt(0)" ::: "memory");
    __builtin_amdgcn_s_barrier();
    asm volatile("" ::: "memory");
  }
}

// ---------------- QKV projection; z selects weight + epilogue ----------------
__global__ __launch_bounds__(256) void gemm_qkv_kernel(
    const u16* __restrict__ xb, const u16* __restrict__ wq, const u16* __restrict__ wk,
    const u16* __restrict__ wv, float* __restrict__ qf, float* __restrict__ kf,
    u16* __restrict__ vt) {
  __shared__ __align__(16) u16 lA[8192], lW[8192];
  const int tid = threadIdx.x;
  const int M0 = blockIdx.y * 128, N0 = blockIdx.x * 128;
  const int z = blockIdx.z;
  const u16* W = (z == 0) ? wq : (z == 1) ? wk : wv;
  f32x4_t acc[4][4] = {};
  gemm_mainloop(xb, W, M0, N0, lA, lW, acc, tid);
  const int w = tid >> 6, l = tid & 63;
  const int lrow = l & 15, kg = l >> 4;
  const int wr = (w >> 1) * 64, wc = (w & 1) * 64;
  const int h = blockIdx.x;  // BN = 128 = HD: one tile column == one head
#pragma unroll
  for (int m = 0; m < 4; ++m)
#pragma unroll
    for (int n = 0; n < 4; ++n)
#pragma unroll
      for (int r = 0; r < 4; ++r) {
        const int grow = M0 + wr + m * 16 + kg * 4 + r;  // token row in [0,4096)
        const int d = wc + n * 16 + lrow;                // 0..127 within head
        const int bb = grow >> 11, t = grow & (TSEQ - 1);
        const float v = acc[m][n][r];
        if (z == 2) {
          // V stored transposed: [b][h][d][t] bf16 (PV B-frags contiguous)
          vt[((size_t)(bb * NHEAD + h) * HD + d) * TSEQ + t] = f2bf(v);
        } else {
          float* dstp = (z == 0) ? qf : kf;
          dstp[((size_t)(bb * NHEAD + h) * TSEQ + t) * HD + d] = v;
        }
      }
}

// ---------------- output projection ----------------
__global__ __launch_bounds__(256) void gemm_out_kernel(const u16* __restrict__ yh,
                                                       const u16* __restrict__ wp,
                                                       float* __restrict__ out) {
  __shared__ __align__(16) u16 lA[8192], lW[8192];
  const int tid = threadIdx.x;
  const int M0 = blockIdx.y * 128, N0 = blockIdx.x * 128;
  f32x4_t acc[4][4] = {};
  gemm_mainloop(yh, wp, M0, N0, lA, lW, acc, tid);
  const int w = tid >> 6, l = tid & 63;
  const int lrow = l & 15, kg = l >> 4;
  const int wr = (w >> 1) * 64, wc = (w & 1) * 64;
#pragma unroll
  for (int m = 0; m < 4; ++m)
#pragma unroll
    for (int n = 0; n < 4; ++n)
#pragma unroll
      for (int r = 0; r < 4; ++r) {
        const int grow = M0 + wr + m * 16 + kg * 4 + r;
        const int gcol = N0 + wc + n * 16 + lrow;
        out[(size_t)grow * HIDDEN + gcol] = acc[m][n][r];
      }
}

// ---------------- RoPE + RMSNorm (fp32 in, bf16 out, head layout) ----------------
__global__ __launch_bounds__(256) void rope_rms_kernel(
    const float* __restrict__ qf, const float* __restrict__ kf, const float* __restrict__ cosp,
    const float* __restrict__ sinp, u16* __restrict__ qh, u16* __restrict__ kh) {
  const int w = threadIdx.x >> 6, l = threadIdx.x & 63;
  const int row = blockIdx.x * 4 + w;  // (b*NH+h)*T + t
  const int t = row & (TSEQ - 1);
  const float* src = blockIdx.y ? kf : qf;
  u16* dst = blockIdx.y ? kh : qh;
  const size_t base = (size_t)row * HD;
  float x1 = src[base + l];
  float x2 = src[base + 64 + l];
  float c = cosp[t * 64 + l], s = sinp[t * 64 + l];
  float y1 = x1 * c + x2 * s;
  float y2 = x2 * c - x1 * s;
  float ss = y1 * y1 + y2 * y2;
#pragma unroll
  for (int off = 1; off < 64; off <<= 1) ss += __shfl_xor(ss, off, 64);
  float rinv = rsqrtf(ss * (1.0f / 128.0f) + EPS_F);
  dst[base + l] = f2bf(y1 * rinv);
  dst[base + 64 + l] = f2bf(y2 * rinv);
}

// ---------------- flash attention, causal + sliding window ----------------
// 4 waves x 16 q-rows = 64 q-rows/block. K,V tiles staged in LDS and shared by
// all 4 waves (4x less L2 traffic). K double-buffered (counted vmcnt(8), loads
// in flight across barriers); V staged at iter top, awaited (vmcnt(4)) after
// QK+softmax so HBM/L2 latency hides under compute. Global source is
// XOR-pre-swizzled so linear global_load_lds lands swizzled; ds_reads apply
// the same XOR -> conflict-free (2-way max). XCD-chunked block swizzle keeps
// each (b,h)'s K/V in one XCD's L2.
__global__ __launch_bounds__(256, 2) void attn_kernel(const u16* __restrict__ qh,
                                                      const u16* __restrict__ kh,
                                                      const u16* __restrict__ vt,
                                                      u16* __restrict__ yh,
                                                      const int* __restrict__ winp) {
  __shared__ __align__(16) u16 Kl[2][8192];  // [buf][64 keys x 128 d], row=256B, swizzled
  __shared__ __align__(16) u16 Vl[8192];     // [128 d x 64 t], row=128B, swizzled
  __shared__ __align__(16) u16 Pl[4][1024];  // per-wave 16x64 P, swizzled
  const int tid = threadIdx.x, w = tid >> 6, l = tid & 63;
  const int lrow = l & 15, kg = l >> 4;
  // XCD-chunked swizzle: 768 blocks = 8 XCDs x 96; each XCD gets 3 whole (b,h)
  const int bid = blockIdx.x;
  const int swz = (bid & 7) * 96 + (bid >> 3);
  const int qb = swz & 31;   // q-block within (b,h)
  const int bh = swz >> 5;   // 0..23
  const int h = bh % NHEAD, b = bh / NHEAD;
  const int win = winp[0];
  const u16* Q = qh + (size_t)bh * TSEQ * HD;
  const u16* K = kh + (size_t)bh * TSEQ * HD;
  const u16* V = vt + (size_t)bh * HD * TSEQ;
  const int qw = qb * 64 + w * 16;  // this wave's 16 q-rows
  // hoist Q fragments (16 rows x 128 d)
  bf16x8_t aq[4];
#pragma unroll
  for (int ks = 0; ks < 4; ++ks)
    aq[ks] = *reinterpret_cast<const bf16x8_t*>(Q + (qw + lrow) * HD + ks * 32 + kg * 8);
  float lrun[4] = {0.f, 0.f, 0.f, 0.f};
  f32x4_t accv[8] = {};
  int lo = qb * 64 - win;
  if (lo < 0) lo = 0;
  lo &= ~63;
  const int last = qb * 64;  // last KV tile start (diagonal tile)
  u16* Pw = &Pl[w][0];

  // stage K tile kv into Kl[buf]: 1024 16B-chunks; chunk c=(i*256+tid):
  // row=c>>4, j=c&15; source column-chunk j^(row&7) -> lands XOR-swizzled.
  auto stage_k = [&](int kv, int buf) {
#pragma unroll
    for (int i = 0; i < 4; ++i) {
      const int c = i * 256 + w * 64 + l;
      const int row = c >> 4, j = c & 15;
      const u16* src = K + (size_t)(kv + row) * HD + ((j ^ (row & 7)) * 8);
      __builtin_amdgcn_global_load_lds(
          (const __attribute__((address_space(1))) void*)src,
          (__attribute__((address_space(3))) void*)(&Kl[buf][0] + i * 2048 + w * 512), 16, 0, 0);
    }
  };
  // stage V tile kv into Vl: rows are d (128), 8 chunks/row.
  auto stage_v = [&](int kv) {
#pragma unroll
    for (int i = 0; i < 4; ++i) {
      const int c = i * 256 + w * 64 + l;
      const int row = c >> 3, j = c & 7;
      const u16* src = V + (size_t)row * TSEQ + kv + ((j ^ (row & 7)) * 8);
      __builtin_amdgcn_global_load_lds(
          (const __attribute__((address_space(1))) void*)src,
          (__attribute__((address_space(3))) void*)(&Vl[0] + i * 2048 + w * 512), 16, 0, 0);
    }
  };

  stage_k(lo, 0);  // prologue: 4 loads in flight
  int it = 0;
  for (int kv = lo; kv <= last; kv += 64, ++it) {
    const int cur = it & 1;
    stage_v(kv);           // +4 (awaited this iter, after QK)
    stage_k(kv + 64, cur ^ 1);  // +4 prefetch (last iter reads harmless garbage)
    asm volatile("s_waitcnt vmcnt(8)" ::: "memory");  // K(kv) landed; V+Knext in flight
    __builtin_amdgcn_s_barrier();
    asm volatile("" ::: "memory");
    // ---- S = Q K^T (16 x 64) from LDS ----
    const u16* Kb = &Kl[cur][0];
    f32x4_t s[4] = {};
#pragma unroll
    for (int n = 0; n < 4; ++n) {
      const int row = n * 16 + lrow;
#pragma unroll
      for (int ks = 0; ks < 4; ++ks) {
        bf16x8_t bk = *reinterpret_cast<const bf16x8_t*>(
            Kb + row * 128 + (((ks << 2) | kg) ^ (row & 7)) * 8);
        s[n] = MFMA16(aq[ks], bk, s[n]);
      }
    }
    // ---- mask + exp (fixed shift, no running max) ----
    float ps[4][4];
    float psum[4];
#pragma unroll
    for (int n = 0; n < 4; ++n) {
      const int key = kv + n * 16 + lrow;
#pragma unroll
      for (int r = 0; r < 4; ++r) {
        const int rowq = qw + kg * 4 + r;
        const bool ok = (key <= rowq) && (rowq - key <= win);
        ps[n][r] = ok ? exp2f(__builtin_fmaf(s[n][r], SCALE_LOG2E, -FIXSUB)) : 0.0f;
      }
    }
#pragma unroll
    for (int r = 0; r < 4; ++r) psum[r] = (ps[0][r] + ps[1][r]) + (ps[2][r] + ps[3][r]);
#pragma unroll
    for (int off = 1; off < 16; off <<= 1)
#pragma unroll
      for (int r = 0; r < 4; ++r) psum[r] += __shfl_xor(psum[r], off, 64);
#pragma unroll
    for (int r = 0; r < 4; ++r) lrun[r] += psum[r];
    // ---- P (bf16) -> swizzled per-wave LDS: D-frag -> A-frag layout ----
#pragma unroll
    for (int n = 0; n < 4; ++n)
#pragma unroll
      for (int r = 0; r < 4; ++r) {
        const int rp = kg * 4 + r;
        int bofs = rp * 128 + (n * 16 + lrow) * 2;
        bofs ^= (rp & 7) << 4;
        *reinterpret_cast<u16*>(reinterpret_cast<char*>(Pw) + bofs) = f2bf(ps[n][r]);
      }
    asm volatile("s_waitcnt lgkmcnt(0)" ::: "memory");
    asm volatile("s_waitcnt vmcnt(4)" ::: "memory");  // V(kv) landed; Knext in flight
    __builtin_amdgcn_s_barrier();
    asm volatile("" ::: "memory");
    // ---- O += P V ----
    bf16x8_t ap[2];
#pragma unroll
    for (int k2 = 0; k2 < 2; ++k2) {
      int bofs = lrow * 128 + k2 * 64 + kg * 16;
      bofs ^= (lrow & 7) << 4;
      ap[k2] = *reinterpret_cast<const bf16x8_t*>(reinterpret_cast<const char*>(Pw) + bofs);
    }
#pragma unroll
    for (int k2 = 0; k2 < 2; ++k2)
#pragma unroll
      for (int dn = 0; dn < 8; ++dn) {
        const int row = dn * 16 + lrow;
        bf16x8_t bv = *reinterpret_cast<const bf16x8_t*>(
            Vl + row * 64 + (((k2 << 2) | kg) ^ (row & 7)) * 8);
        accv[dn] = MFMA16(ap[k2], bv, accv[dn]);
      }
    __builtin_amdgcn_s_barrier();  // Vl/Kl safe to restage next iter
    asm volatile("" ::: "memory");
  }
  // epilogue: divide by row sums, write y bf16 [4096][1536]
  float inv[4];
#pragma unroll
  for (int r = 0; r < 4; ++r) inv[r] = 1.0f / lrun[r];
#pragma unroll
  for (int dn = 0; dn < 8; ++dn)
#pragma unroll
    for (int r = 0; r < 4; ++r) {
      const int rowg = b * TSEQ + qw + kg * 4 + r;
      const int col = h * HD + dn * 16 + lrow;
      yh[(size_t)rowg * HIDDEN + col] = f2bf(accv[dn][r] * inv[r]);
    }
}

extern "C" void kernel_launch(void* const* d_in, const int* in_sizes, int n_in, void* d_out,
                              int out_size, void* d_ws, size_t ws_size, hipStream_t stream) {
  const float* x = (const float*)d_in[0];
  const float* cosp = (const float*)d_in[1];
  const float* sinp = (const float*)d_in[2];
  const float* Wq = (const float*)d_in[3];
  const float* Wk = (const float*)d_in[4];
  const float* Wv = (const float*)d_in[5];
  const float* Wp = (const float*)d_in[6];
  const int* winp = (const int*)d_in[7];

  char* ws = (char*)d_ws;
  size_t off = 0;
  auto alloc = [&](size_t bytes) {
    char* p = ws + off;
    off += (bytes + 255) & ~(size_t)255;
    return p;
  };
  u16* xb = (u16*)alloc((size_t)NROWS * HIDDEN * 2);
  u16* wqb = (u16*)alloc((size_t)HIDDEN * HIDDEN * 2);
  u16* wkb = (u16*)alloc((size_t)HIDDEN * HIDDEN * 2);
  u16* wvb = (u16*)alloc((size_t)HIDDEN * HIDDEN * 2);
  u16* wpb = (u16*)alloc((size_t)HIDDEN * HIDDEN * 2);
  float* qf = (float*)alloc((size_t)NROWS * HIDDEN * 4);
  float* kf = (float*)alloc((size_t)NROWS * HIDDEN * 4);
  u16* qh = (u16*)alloc((size_t)NROWS * HIDDEN * 2);
  u16* kh = (u16*)alloc((size_t)NROWS * HIDDEN * 2);
  u16* vt = (u16*)alloc((size_t)NROWS * HIDDEN * 2);
  u16* yh = (u16*)alloc((size_t)NROWS * HIDDEN * 2);

  const int nx = NROWS * HIDDEN;    // 6291456
  const int nw = HIDDEN * HIDDEN;   // 2359296
  cast_kernel<<<nx / 1024, 256, 0, stream>>>(x, xb, nx);
  cast_kernel<<<nw / 1024, 256, 0, stream>>>(Wq, wqb, nw);
  cast_kernel<<<nw / 1024, 256, 0, stream>>>(Wk, wkb, nw);
  cast_kernel<<<nw / 1024, 256, 0, stream>>>(Wv, wvb, nw);
  cast_kernel<<<nw / 1024, 256, 0, stream>>>(Wp, wpb, nw);

  gemm_qkv_kernel<<<dim3(HIDDEN / 128, NROWS / 128, 3), 256, 0, stream>>>(xb, wqb, wkb, wvb, qf,
                                                                          kf, vt);
  rope_rms_kernel<<<dim3((2 * NHEAD * TSEQ) / 4, 2), 256, 0, stream>>>(qf, kf, cosp, sinp, qh,
                                                                       kh);
  attn_kernel<<<dim3(768), 256, 0, stream>>>(qh, kh, vt, yh, winp);
  gemm_out_kernel<<<dim3(HIDDEN / 128, NROWS / 128), 256, 0, stream>>>(yh, wpb, (float*)d_out);
}